// Round 1
// baseline (235.132 us; speedup 1.0000x reference)
//
#include <hip/hip_runtime.h>
#include <hip/hip_bf16.h>
#include <stdint.h>

#define B_   4
#define H_   16
#define LQ_  1024
#define LKV_ 2048
#define DM_  1024
#define DH_  64

typedef __attribute__((ext_vector_type(8))) __bf16 bf16x8;
typedef __attribute__((ext_vector_type(4))) float  f32x4;
typedef __attribute__((ext_vector_type(8))) short  short8;

__device__ __forceinline__ void gload_lds16(const void* g, void* l) {
  __builtin_amdgcn_global_load_lds(
      (const __attribute__((address_space(1))) void*)g,
      (__attribute__((address_space(3))) void*)l, 16, 0, 0);
}

// ---------------- fused fp32 -> bf16 cast ----------------
struct CastArgs {
  const float* src[6];
  __hip_bfloat16* dst[6];
  int n[6];
};

__global__ void cast_multi(CastArgs a) {
  int seg = blockIdx.y;
  int n = a.n[seg];
  int i = (blockIdx.x * blockDim.x + threadIdx.x) * 8;
  if (i >= n) return;
  const float* s = a.src[seg] + i;
  float4 x = *(const float4*)s;
  float4 y = *(const float4*)(s + 4);
  union { short8 v; __hip_bfloat16 h[8]; } u;
  u.h[0] = __float2bfloat16(x.x); u.h[1] = __float2bfloat16(x.y);
  u.h[2] = __float2bfloat16(x.z); u.h[3] = __float2bfloat16(x.w);
  u.h[4] = __float2bfloat16(y.x); u.h[5] = __float2bfloat16(y.y);
  u.h[6] = __float2bfloat16(y.z); u.h[7] = __float2bfloat16(y.w);
  *(short8*)(a.dst[seg] + i) = u.v;
}

__global__ void mask_bias(const int* __restrict__ msk, float* __restrict__ mb, int n) {
  int i = blockIdx.x * blockDim.x + threadIdx.x;
  if (i < n) mb[i] = msk[i] ? 0.0f : -1e30f;
}

// ---------------- GEMM: C[m,n] = sum_k A[m,k]*Bt[n,k] + bias[n] ----------------
// Tile BM=128, BN=64, BK=32. 4 waves (2x2), wave tile 64x32 (mt=4, nt=2).
// MODE 0: bf16 out [M][N]; MODE 1: bf16 out transposed per-head (V);
// MODE 2: fp32 out [M][N].
template<int MODE>
__global__ __launch_bounds__(256, 4)
void gemm_bt(const __hip_bfloat16* __restrict__ A,
             const __hip_bfloat16* __restrict__ Bt,
             const float* __restrict__ bias,
             void* __restrict__ Cout, int M, int N, int K) {
  __shared__ __hip_bfloat16 lA[128 * 32];
  __shared__ __hip_bfloat16 lB[64 * 32];
  const int tid = threadIdx.x;
  const int lane = tid & 63, wv = tid >> 6;
  const int l16 = lane & 15, lg = lane >> 4;
  const int wm = wv >> 1, wn = wv & 1;
  const int tileM = blockIdx.y * 128, tileN = blockIdx.x * 64;
  const int KB = K * 2;  // row bytes

  f32x4 acc[4][2] = {};

  const int oa = wv * 1024 + lane * 16;  // byte offset within staged region per call

  for (int kt = 0; kt < K; kt += 32) {
    {
      int o = oa;  // A rows 0..63
      const char* src = (const char*)A + (size_t)(tileM + (o >> 6)) * KB + kt * 2 + (o & 63);
      gload_lds16(src, (char*)lA + wv * 1024);
      o = oa + 4096;  // A rows 64..127
      src = (const char*)A + (size_t)(tileM + (o >> 6)) * KB + kt * 2 + (o & 63);
      gload_lds16(src, (char*)lA + 4096 + wv * 1024);
      o = oa;  // B rows 0..63
      src = (const char*)Bt + (size_t)(tileN + (o >> 6)) * KB + kt * 2 + (o & 63);
      gload_lds16(src, (char*)lB + wv * 1024);
    }
    __syncthreads();
    bf16x8 af[4], bf[2];
#pragma unroll
    for (int mt = 0; mt < 4; ++mt)
      af[mt] = *(const bf16x8*)((const char*)lA + ((wm * 64 + mt * 16 + l16) * 32 + lg * 8) * 2);
#pragma unroll
    for (int nt = 0; nt < 2; ++nt)
      bf[nt] = *(const bf16x8*)((const char*)lB + ((wn * 32 + nt * 16 + l16) * 32 + lg * 8) * 2);
#pragma unroll
    for (int mt = 0; mt < 4; ++mt)
#pragma unroll
      for (int nt = 0; nt < 2; ++nt)
        acc[mt][nt] = __builtin_amdgcn_mfma_f32_16x16x32_bf16(af[mt], bf[nt], acc[mt][nt], 0, 0, 0);
    __syncthreads();
  }

#pragma unroll
  for (int mt = 0; mt < 4; ++mt) {
#pragma unroll
    for (int nt = 0; nt < 2; ++nt) {
      int col = tileN + wn * 32 + nt * 16 + l16;
      float bcol = bias[col];
      int row0 = tileM + wm * 64 + mt * 16 + lg * 4;
      f32x4 a = acc[mt][nt];
#pragma unroll
      for (int r = 0; r < 4; ++r) {
        int row = row0 + r;
        float v = a[r] + bcol;
        if (MODE == 0) {
          ((__hip_bfloat16*)Cout)[(size_t)row * N + col] = __float2bfloat16(v);
        } else if (MODE == 1) {
          // row = b*2048 + kv ; write Vt[(b*1024 + n)*2048 + kv]
          int b = row >> 11, kv = row & 2047;
          ((__hip_bfloat16*)Cout)[((size_t)(b * 1024 + col)) * 2048 + kv] = __float2bfloat16(v);
        } else {
          ((float*)Cout)[(size_t)row * N + col] = v;
        }
      }
    }
  }
}

// ---------------- flash attention ----------------
// Grid (LQ/64, H, B), 256 threads = 4 waves, each wave owns 16 q-rows.
// K LDS tile [64 kv][64 d], V LDS tile [64 d][64 kv] (from transposed Vt),
// both XOR-swizzled (byte ^= (row&7)<<4) via pre-swizzled global_load_lds source.
__global__ __launch_bounds__(256, 3)
void attn_fwd(const __hip_bfloat16* __restrict__ Qg,
              const __hip_bfloat16* __restrict__ Kg,
              const __hip_bfloat16* __restrict__ Vt,
              const float* __restrict__ mbf,
              __hip_bfloat16* __restrict__ AO) {
  __shared__ __hip_bfloat16 lK[64 * 64];
  __shared__ __hip_bfloat16 lV[64 * 64];
  __shared__ __hip_bfloat16 lP[4][16 * 64];
  const int tid = threadIdx.x, lane = tid & 63, wv = tid >> 6;
  const int l16 = lane & 15, lg = lane >> 4;
  const int b = blockIdx.z, h = blockIdx.y, qb = blockIdx.x * 64;
  const int q0 = qb + wv * 16;

  // Q fragments: A[q=l16][d = lg*8 + i], chunks d∈[0,32),[32,64)
  const char* qbase = (const char*)Qg + ((size_t)(b * LQ_ + q0 + l16) * DM_ + h * DH_ + lg * 8) * 2;
  bf16x8 qf0 = *(const bf16x8*)qbase;
  bf16x8 qf1 = *(const bf16x8*)(qbase + 64);

  f32x4 o[4] = {};
  float m_r[4], l_r[4];
#pragma unroll
  for (int r = 0; r < 4; ++r) { m_r[r] = -1e30f; l_r[r] = 0.f; }

  const float* mbp = mbf + b * LKV_;
  const char* Kbase = (const char*)Kg + ((size_t)(b * LKV_) * DM_ + h * DH_) * 2;
  const char* Vbase = (const char*)Vt + ((size_t)((b * H_ + h) * DH_) * LKV_) * 2;

  const int o0 = wv * 1024 + lane * 16;
  const int r0 = o0 >> 7, c0 = o0 & 127, c0s = c0 ^ ((r0 & 7) << 4);
  const int o1 = o0 + 4096;
  const int r1 = o1 >> 7, c1 = o1 & 127, c1s = c1 ^ ((r1 & 7) << 4);

  for (int kv0 = 0; kv0 < LKV_; kv0 += 64) {
    // stage K tile (rows = kv, 128B each) and V tile (rows = d, 128B each)
    gload_lds16(Kbase + (size_t)(kv0 + r0) * 2048 + c0s, (char*)lK + wv * 1024);
    gload_lds16(Kbase + (size_t)(kv0 + r1) * 2048 + c1s, (char*)lK + 4096 + wv * 1024);
    gload_lds16(Vbase + (size_t)r0 * 4096 + kv0 * 2 + c0s, (char*)lV + wv * 1024);
    gload_lds16(Vbase + (size_t)r1 * 4096 + kv0 * 2 + c1s, (char*)lV + 4096 + wv * 1024);
    __syncthreads();

    // S = Q K^T  (scaled + mask)
    f32x4 s[4];
#pragma unroll
    for (int nt = 0; nt < 4; ++nt) {
      int row = nt * 16 + l16;     // kv within tile
      int sw = (row & 7) << 4;
      const char* kp = (const char*)lK + row * 128;
      bf16x8 k0 = *(const bf16x8*)(kp + ((lg * 16) ^ sw));
      bf16x8 k1 = *(const bf16x8*)(kp + ((64 + lg * 16) ^ sw));
      f32x4 z = {};
      z = __builtin_amdgcn_mfma_f32_16x16x32_bf16(qf0, k0, z, 0, 0, 0);
      z = __builtin_amdgcn_mfma_f32_16x16x32_bf16(qf1, k1, z, 0, 0, 0);
      float mb = mbp[kv0 + row];
#pragma unroll
      for (int r = 0; r < 4; ++r) s[nt][r] = z[r] * 0.125f + mb;
    }

    // online softmax (rows live in 16-lane groups; reduce over l16)
    float mx[4];
#pragma unroll
    for (int r = 0; r < 4; ++r)
      mx[r] = fmaxf(fmaxf(s[0][r], s[1][r]), fmaxf(s[2][r], s[3][r]));
#pragma unroll
    for (int msk = 1; msk < 16; msk <<= 1)
#pragma unroll
      for (int r = 0; r < 4; ++r)
        mx[r] = fmaxf(mx[r], __shfl_xor(mx[r], msk));

    float alpha[4], rs[4];
#pragma unroll
    for (int r = 0; r < 4; ++r) {
      float mn = fmaxf(m_r[r], mx[r]);
      alpha[r] = __expf(m_r[r] - mn);
      m_r[r] = mn;
      rs[r] = 0.f;
    }

    // P = exp(S - m), write to per-wave swizzled LDS for layout transpose
#pragma unroll
    for (int nt = 0; nt < 4; ++nt) {
      int kvb = (nt * 16 + l16) * 2;
#pragma unroll
      for (int r = 0; r < 4; ++r) {
        float p = __expf(s[nt][r] - m_r[r]);
        rs[r] += p;
        int q = lg * 4 + r;
        *(__hip_bfloat16*)((char*)lP[wv] + q * 128 + (kvb ^ ((q & 7) << 4))) = __float2bfloat16(p);
      }
    }
#pragma unroll
    for (int msk = 1; msk < 16; msk <<= 1)
#pragma unroll
      for (int r = 0; r < 4; ++r)
        rs[r] += __shfl_xor(rs[r], msk);
#pragma unroll
    for (int r = 0; r < 4; ++r) l_r[r] = l_r[r] * alpha[r] + rs[r];
#pragma unroll
    for (int nt = 0; nt < 4; ++nt)
#pragma unroll
      for (int r = 0; r < 4; ++r) o[nt][r] *= alpha[r];

    // O += P V   (P A-frags from lP, V B-frags from lV)
#pragma unroll
    for (int c = 0; c < 2; ++c) {
      int swp = (l16 & 7) << 4;
      bf16x8 pf = *(const bf16x8*)((const char*)lP[wv] + l16 * 128 + ((c * 64 + lg * 16) ^ swp));
#pragma unroll
      for (int nt = 0; nt < 4; ++nt) {
        int row = nt * 16 + l16;   // d within tile
        int sw = (row & 7) << 4;
        bf16x8 vf = *(const bf16x8*)((const char*)lV + row * 128 + ((c * 64 + lg * 16) ^ sw));
        o[nt] = __builtin_amdgcn_mfma_f32_16x16x32_bf16(pf, vf, o[nt], 0, 0, 0);
      }
    }
    __syncthreads();
  }

#pragma unroll
  for (int r = 0; r < 4; ++r) l_r[r] = 1.0f / l_r[r];
#pragma unroll
  for (int nt = 0; nt < 4; ++nt) {
    int col = h * DH_ + nt * 16 + l16;
#pragma unroll
    for (int r = 0; r < 4; ++r) {
      int row = b * LQ_ + q0 + lg * 4 + r;
      AO[(size_t)row * DM_ + col] = __float2bfloat16(o[nt][r] * l_r[r]);
    }
  }
}

// ---------------- launch ----------------
extern "C" void kernel_launch(void* const* d_in, const int* in_sizes, int n_in,
                              void* d_out, int out_size, void* d_ws, size_t ws_size,
                              hipStream_t stream) {
  const float* dec = (const float*)d_in[0];
  const float* enc = (const float*)d_in[1];
  const int*   msk = (const int*)d_in[2];
  const float* Wq = (const float*)d_in[3];
  const float* bq = (const float*)d_in[4];
  const float* Wk = (const float*)d_in[5];
  const float* bk = (const float*)d_in[6];
  const float* Wv = (const float*)d_in[7];
  const float* bv = (const float*)d_in[8];
  const float* Wo = (const float*)d_in[9];
  const float* bo = (const float*)d_in[10];

  char* ws = (char*)d_ws;
  __hip_bfloat16* decB = (__hip_bfloat16*)(ws);             // 8 MiB
  __hip_bfloat16* encB = (__hip_bfloat16*)(ws + 8388608);   // 16 MiB
  __hip_bfloat16* WqB  = (__hip_bfloat16*)(ws + 25165824);  // 2 MiB
  __hip_bfloat16* WkB  = (__hip_bfloat16*)(ws + 27262976);
  __hip_bfloat16* WvB  = (__hip_bfloat16*)(ws + 29360128);
  __hip_bfloat16* WoB  = (__hip_bfloat16*)(ws + 31457280);
  __hip_bfloat16* Qb   = (__hip_bfloat16*)(ws + 33554432);  // 8 MiB
  __hip_bfloat16* Kb   = (__hip_bfloat16*)(ws + 41943040);  // 16 MiB
  __hip_bfloat16* Vtb  = (__hip_bfloat16*)(ws + 58720256);  // 16 MiB  [B,H,Dh,Lkv]
  __hip_bfloat16* AO   = (__hip_bfloat16*)(ws + 75497472);  // 8 MiB
  float*          mbf  = (float*)(ws + 83886080);           // 32 KiB

  CastArgs ca;
  ca.src[0] = dec; ca.dst[0] = decB; ca.n[0] = 4096 * 1024;
  ca.src[1] = enc; ca.dst[1] = encB; ca.n[1] = 8192 * 1024;
  ca.src[2] = Wq;  ca.dst[2] = WqB;  ca.n[2] = 1024 * 1024;
  ca.src[3] = Wk;  ca.dst[3] = WkB;  ca.n[3] = 1024 * 1024;
  ca.src[4] = Wv;  ca.dst[4] = WvB;  ca.n[4] = 1024 * 1024;
  ca.src[5] = Wo;  ca.dst[5] = WoB;  ca.n[5] = 1024 * 1024;
  cast_multi<<<dim3(4096, 6), dim3(256), 0, stream>>>(ca);
  mask_bias<<<dim3(32), dim3(256), 0, stream>>>(msk, mbf, B_ * LKV_);

  gemm_bt<0><<<dim3(16, 32), dim3(256), 0, stream>>>(decB, WqB, bq, (void*)Qb,  4096, 1024, 1024);
  gemm_bt<0><<<dim3(16, 64), dim3(256), 0, stream>>>(encB, WkB, bk, (void*)Kb,  8192, 1024, 1024);
  gemm_bt<1><<<dim3(16, 64), dim3(256), 0, stream>>>(encB, WvB, bv, (void*)Vtb, 8192, 1024, 1024);

  attn_fwd<<<dim3(16, 16, 4), dim3(256), 0, stream>>>(Qb, Kb, Vtb, mbf, AO);

  gemm_bt<2><<<dim3(16, 32), dim3(256), 0, stream>>>(AO, WoB, bo, d_out, 4096, 1024, 1024);
}

// Round 3
// 200.196 us; speedup vs baseline: 1.1745x; 1.1745x over previous
//
#include <hip/hip_runtime.h>
#include <hip/hip_bf16.h>
#include <stdint.h>

#define B_   4
#define H_   16
#define LQ_  1024
#define LKV_ 2048
#define DM_  1024
#define DH_  64

typedef __attribute__((ext_vector_type(8))) __bf16 bf16x8;
typedef __attribute__((ext_vector_type(4))) float  f32x4;
typedef __attribute__((ext_vector_type(16))) float f32x16;
typedef __attribute__((ext_vector_type(8))) short  short8;

__device__ __forceinline__ void gload_lds16(const void* g, void* l) {
  __builtin_amdgcn_global_load_lds(
      (const __attribute__((address_space(1))) void*)g,
      (__attribute__((address_space(3))) void*)l, 16, 0, 0);
}

// Explicit LDS-DMA drain: global_load_lds completion is tracked in vmcnt and
// is NOT guaranteed to be covered by __syncthreads' implicit fence in a
// loop-carried double-buffer (round-2 post-timing divergence). Drain + pin.
__device__ __forceinline__ void drain_vmem() {
  asm volatile("s_waitcnt vmcnt(0)" ::: "memory");
  __builtin_amdgcn_sched_barrier(0);
}

__device__ __forceinline__ unsigned pack2(float a, float b) {
  unsigned lo = (unsigned)__bfloat16_as_ushort(__float2bfloat16(a));
  unsigned hi = (unsigned)__bfloat16_as_ushort(__float2bfloat16(b));
  return lo | (hi << 16);
}

// ---------------- fused fp32 -> bf16 cast ----------------
struct CastArgs {
  const float* src[6];
  __hip_bfloat16* dst[6];
  int n[6];
};

__global__ void cast_multi(CastArgs a) {
  int seg = blockIdx.y;
  int n = a.n[seg];
  int i = (blockIdx.x * blockDim.x + threadIdx.x) * 8;
  if (i >= n) return;
  const float* s = a.src[seg] + i;
  float4 x = *(const float4*)s;
  float4 y = *(const float4*)(s + 4);
  union { short8 v; __hip_bfloat16 h[8]; } u;
  u.h[0] = __float2bfloat16(x.x); u.h[1] = __float2bfloat16(x.y);
  u.h[2] = __float2bfloat16(x.z); u.h[3] = __float2bfloat16(x.w);
  u.h[4] = __float2bfloat16(y.x); u.h[5] = __float2bfloat16(y.y);
  u.h[6] = __float2bfloat16(y.z); u.h[7] = __float2bfloat16(y.w);
  *(short8*)(a.dst[seg] + i) = u.v;
}

__global__ void mask_bias(const int* __restrict__ msk, float* __restrict__ mb, int n) {
  int i = blockIdx.x * blockDim.x + threadIdx.x;
  if (i < n) mb[i] = msk[i] ? 0.0f : -1e30f;
}

// ---------------- GEMM: C[m,n] = sum_k A[m,k]*Bt[n,k] + bias[n] ----------------
// Tile BM=128, BN=64, BK=64. 4 waves (2x2). Double-buffered LDS, T3-lite
// schedule (stage next tile BEFORE compute, one explicit-drain barrier/K-step).
template<int MODE>
__global__ __launch_bounds__(256, 2)
void gemm_bt(const __hip_bfloat16* __restrict__ A,
             const __hip_bfloat16* __restrict__ Bt,
             const float* __restrict__ bias,
             void* __restrict__ Cout, int M, int N, int K) {
  __shared__ __hip_bfloat16 lA[2][128 * 64];
  __shared__ __hip_bfloat16 lB[2][64 * 64];
  const int tid = threadIdx.x;
  const int lane = tid & 63, wv = tid >> 6;
  const int l16 = lane & 15, lg = lane >> 4;
  const int wm = wv >> 1, wn = wv & 1;
  const int tileM = blockIdx.y * 128, tileN = blockIdx.x * 64;
  const int KB = K * 2;

  f32x4 acc[4][2] = {};
  const int o0 = wv * 1024 + lane * 16;

  auto GSTAGE = [&](int bi, int kt) {
#pragma unroll
    for (int j = 0; j < 4; ++j) {
      int o = o0 + j * 4096;
      int row = o >> 7, col = (o & 127) ^ ((row & 7) << 4);
      gload_lds16((const char*)A + (size_t)(tileM + row) * KB + kt * 2 + col,
                  (char*)lA[bi] + wv * 1024 + j * 4096);
    }
#pragma unroll
    for (int j = 0; j < 2; ++j) {
      int o = o0 + j * 4096;
      int row = o >> 7, col = (o & 127) ^ ((row & 7) << 4);
      gload_lds16((const char*)Bt + (size_t)(tileN + row) * KB + kt * 2 + col,
                  (char*)lB[bi] + wv * 1024 + j * 4096);
    }
  };

  GSTAGE(0, 0);
  drain_vmem();
  __syncthreads();
  int buf = 0;
  const int NT = K / 64;
  for (int t = 0; t < NT; ++t) {
    if (t + 1 < NT) GSTAGE(buf ^ 1, (t + 1) * 64);
    bf16x8 af[4][2], bfr[2][2];
#pragma unroll
    for (int mt = 0; mt < 4; ++mt) {
      const int row = wm * 64 + mt * 16 + l16;
      const int sw = (row & 7) << 4;
#pragma unroll
      for (int kk = 0; kk < 2; ++kk)
        af[mt][kk] = *(const bf16x8*)((const char*)lA[buf] + row * 128 + ((kk * 64 + lg * 16) ^ sw));
    }
#pragma unroll
    for (int nt = 0; nt < 2; ++nt) {
      const int row = wn * 32 + nt * 16 + l16;
      const int sw = (row & 7) << 4;
#pragma unroll
      for (int kk = 0; kk < 2; ++kk)
        bfr[nt][kk] = *(const bf16x8*)((const char*)lB[buf] + row * 128 + ((kk * 64 + lg * 16) ^ sw));
    }
#pragma unroll
    for (int kk = 0; kk < 2; ++kk)
#pragma unroll
      for (int mt = 0; mt < 4; ++mt)
#pragma unroll
        for (int nt = 0; nt < 2; ++nt)
          acc[mt][nt] = __builtin_amdgcn_mfma_f32_16x16x32_bf16(af[mt][kk], bfr[nt][kk], acc[mt][nt], 0, 0, 0);
    drain_vmem();
    __syncthreads();
    buf ^= 1;
  }

#pragma unroll
  for (int mt = 0; mt < 4; ++mt) {
#pragma unroll
    for (int nt = 0; nt < 2; ++nt) {
      int col = tileN + wn * 32 + nt * 16 + l16;
      float bcol = bias[col];
      int row0 = tileM + wm * 64 + mt * 16 + lg * 4;
      f32x4 a = acc[mt][nt];
#pragma unroll
      for (int r = 0; r < 4; ++r) {
        int row = row0 + r;
        float v = a[r] + bcol;
        if (MODE == 0) {
          ((__hip_bfloat16*)Cout)[(size_t)row * N + col] = __float2bfloat16(v);
        } else if (MODE == 1) {
          int b = row >> 11, kv = row & 2047;
          ((__hip_bfloat16*)Cout)[((size_t)(b * 1024 + col)) * 2048 + kv] = __float2bfloat16(v);
        } else {
          ((float*)Cout)[(size_t)row * N + col] = v;
        }
      }
    }
  }
}

// ---------------- flash attention, swapped-QK^T 32x32 ----------------
// Grid (LQ/128, H, B), 4 waves, each wave owns 32 q rows (q = lane&31).
__global__ __launch_bounds__(256, 2)
void attn_fwd(const __hip_bfloat16* __restrict__ Qg,
              const __hip_bfloat16* __restrict__ Kg,
              const __hip_bfloat16* __restrict__ Vt,
              const float* __restrict__ mbf,
              __hip_bfloat16* __restrict__ AO) {
  __shared__ __hip_bfloat16 lK[2][64 * 64];
  __shared__ __hip_bfloat16 lV[2][64 * 64];
  const int tid = threadIdx.x, lane = tid & 63, wv = tid >> 6;
  const int l32 = lane & 31, h = lane >> 5;
  const int b = blockIdx.z, hd = blockIdx.y, qb = blockIdx.x * 128;
  const int q0 = qb + wv * 32;

  const char* qbase = (const char*)Qg +
      ((size_t)(b * LQ_ + q0 + l32) * DM_ + hd * DH_ + h * 8) * 2;
  bf16x8 qf[4];
#pragma unroll
  for (int dk = 0; dk < 4; ++dk) qf[dk] = *(const bf16x8*)(qbase + dk * 32);

  f32x16 o[2] = {};
  float m_r = -1e30f, l_r = 0.f;
  const float* mbp = mbf + b * LKV_;
  const char* Kbase = (const char*)Kg + ((size_t)(b * LKV_) * DM_ + hd * DH_) * 2;
  const char* Vbase = (const char*)Vt + ((size_t)((b * H_ + hd) * DH_)) * LKV_ * 2;

  const int ofs = wv * 1024 + lane * 16;
  const int r0 = ofs >> 7, c0s = (ofs & 127) ^ ((r0 & 7) << 4);
  const int ofs1 = ofs + 4096;
  const int r1 = ofs1 >> 7, c1s = (ofs1 & 127) ^ ((r1 & 7) << 4);

  auto STAGE = [&](int bi, int kv0) {
    gload_lds16(Kbase + (size_t)(kv0 + r0) * 2048 + c0s, (char*)lK[bi] + wv * 1024);
    gload_lds16(Kbase + (size_t)(kv0 + r1) * 2048 + c1s, (char*)lK[bi] + 4096 + wv * 1024);
    gload_lds16(Vbase + (size_t)r0 * 4096 + kv0 * 2 + c0s, (char*)lV[bi] + wv * 1024);
    gload_lds16(Vbase + (size_t)r1 * 4096 + kv0 * 2 + c1s, (char*)lV[bi] + 4096 + wv * 1024);
  };

  STAGE(0, 0);
  drain_vmem();
  __syncthreads();
  int buf = 0;

  for (int it = 0; it < LKV_ / 64; ++it) {
    const int kv0 = it * 64;
    if (it + 1 < LKV_ / 64) STAGE(buf ^ 1, kv0 + 64);

    // S^T = K Q^T : col = q = l32 ; row = kv = (g&3) + 8*(g>>2) + 4*h
    f32x16 z[2];
#pragma unroll
    for (int t = 0; t < 2; ++t) {
      z[t] = {};
      const int row = t * 32 + l32;
      const int sw = (row & 7) << 4;
      const char* kp = (const char*)lK[buf] + row * 128;
      __builtin_amdgcn_s_setprio(1);
#pragma unroll
      for (int dk = 0; dk < 4; ++dk) {
        bf16x8 kf = *(const bf16x8*)(kp + ((dk * 32 + h * 16) ^ sw));
        z[t] = __builtin_amdgcn_mfma_f32_32x32x16_bf16(kf, qf[dk], z[t], 0, 0, 0);
      }
      __builtin_amdgcn_s_setprio(0);
    }

    // row max: lane-local + one cross-half reduce
    float mx = z[0][0];
#pragma unroll
    for (int t = 0; t < 2; ++t)
#pragma unroll
      for (int g = 0; g < 16; ++g) mx = fmaxf(mx, z[t][g]);
    mx = fmaxf(mx, __shfl_xor(mx, 32));
    mx *= 0.125f;

    // T13 defer-max
    if (!__all(mx - m_r <= 8.0f)) {
      float mn = fmaxf(m_r, mx);
      float alpha = __expf(m_r - mn);
      m_r = mn;
      l_r *= alpha;
#pragma unroll
      for (int g = 0; g < 16; ++g) {
        float a2 = __shfl(alpha, (g & 3) + 8 * (g >> 2) + 4 * h);
        o[0][g] *= a2;
        o[1][g] *= a2;
      }
    }

    // P = exp(s*scale + mask - m), packed to bf16 pairs in-register
    float rs = 0.f;
    unsigned pk[2][4][2];
#pragma unroll
    for (int t = 0; t < 2; ++t)
#pragma unroll
      for (int s = 0; s < 4; ++s) {
        f32x4 mv = *(const f32x4*)(mbp + kv0 + t * 32 + s * 8 + h * 4);
        float p0 = __expf(fmaf(z[t][s * 4 + 0], 0.125f, mv[0] - m_r));
        float p1 = __expf(fmaf(z[t][s * 4 + 1], 0.125f, mv[1] - m_r));
        float p2 = __expf(fmaf(z[t][s * 4 + 2], 0.125f, mv[2] - m_r));
        float p3 = __expf(fmaf(z[t][s * 4 + 3], 0.125f, mv[3] - m_r));
        rs += (p0 + p1) + (p2 + p3);
        pk[t][s][0] = pack2(p0, p1);
        pk[t][s][1] = pack2(p2, p3);
      }
    rs += __shfl_xor(rs, 32);
    l_r += rs;

    // O += P V : A-frag per 16-kv chunk built via half-swap exchange
#pragma unroll
    for (int c = 0; c < 4; ++c) {
      const int t = c >> 1, cc = c & 1;
      unsigned a_l0 = pk[t][2 * cc + 0][0], a_l1 = pk[t][2 * cc + 0][1];
      unsigned a_h0 = pk[t][2 * cc + 1][0], a_h1 = pk[t][2 * cc + 1][1];
      unsigned x0 = (unsigned)__shfl_xor((int)a_h0, 32);
      unsigned x1 = (unsigned)__shfl_xor((int)a_h1, 32);
      unsigned y0 = (unsigned)__shfl_xor((int)a_l0, 32);
      unsigned y1 = (unsigned)__shfl_xor((int)a_l1, 32);
      union { unsigned w[4]; bf16x8 v; } au;
      au.w[0] = h ? x0 : a_l0;
      au.w[1] = h ? x1 : a_l1;
      au.w[2] = h ? a_h0 : y0;
      au.w[3] = h ? a_h1 : y1;
      __builtin_amdgcn_s_setprio(1);
#pragma unroll
      for (int dt = 0; dt < 2; ++dt) {
        const int row = dt * 32 + l32;
        const int sw = (row & 7) << 4;
        bf16x8 vf = *(const bf16x8*)((const char*)lV[buf] + row * 128 + ((c * 32 + h * 16) ^ sw));
        o[dt] = __builtin_amdgcn_mfma_f32_32x32x16_bf16(au.v, vf, o[dt], 0, 0, 0);
      }
      __builtin_amdgcn_s_setprio(0);
    }
    drain_vmem();
    __syncthreads();
    buf ^= 1;
  }

  float linv = 1.0f / l_r;
  float lq[16];
#pragma unroll
  for (int g = 0; g < 16; ++g)
    lq[g] = __shfl(linv, (g & 3) + 8 * (g >> 2) + 4 * h);
#pragma unroll
  for (int dt = 0; dt < 2; ++dt)
#pragma unroll
    for (int g = 0; g < 16; ++g) {
      int q = (g & 3) + 8 * (g >> 2) + 4 * h;
      AO[(size_t)(b * LQ_ + qb + wv * 32 + q) * DM_ + hd * DH_ + dt * 32 + l32] =
          __float2bfloat16(o[dt][g] * lq[g]);
    }
}

// ---------------- launch ----------------
extern "C" void kernel_launch(void* const* d_in, const int* in_sizes, int n_in,
                              void* d_out, int out_size, void* d_ws, size_t ws_size,
                              hipStream_t stream) {
  const float* dec = (const float*)d_in[0];
  const float* enc = (const float*)d_in[1];
  const int*   msk = (const int*)d_in[2];
  const float* Wq = (const float*)d_in[3];
  const float* bq = (const float*)d_in[4];
  const float* Wk = (const float*)d_in[5];
  const float* bk = (const float*)d_in[6];
  const float* Wv = (const float*)d_in[7];
  const float* bv = (const float*)d_in[8];
  const float* Wo = (const float*)d_in[9];
  const float* bo = (const float*)d_in[10];

  char* ws = (char*)d_ws;
  __hip_bfloat16* decB = (__hip_bfloat16*)(ws);
  __hip_bfloat16* encB = (__hip_bfloat16*)(ws + 8388608);
  __hip_bfloat16* WqB  = (__hip_bfloat16*)(ws + 25165824);
  __hip_bfloat16* WkB  = (__hip_bfloat16*)(ws + 27262976);
  __hip_bfloat16* WvB  = (__hip_bfloat16*)(ws + 29360128);
  __hip_bfloat16* WoB  = (__hip_bfloat16*)(ws + 31457280);
  __hip_bfloat16* Qb   = (__hip_bfloat16*)(ws + 33554432);
  __hip_bfloat16* Kb   = (__hip_bfloat16*)(ws + 41943040);
  __hip_bfloat16* Vtb  = (__hip_bfloat16*)(ws + 58720256);  // [B,H,Dh,Lkv]
  __hip_bfloat16* AO   = (__hip_bfloat16*)(ws + 75497472);
  float*          mbf  = (float*)(ws + 83886080);

  CastArgs ca;
  ca.src[0] = dec; ca.dst[0] = decB; ca.n[0] = 4096 * 1024;
  ca.src[1] = enc; ca.dst[1] = encB; ca.n[1] = 8192 * 1024;
  ca.src[2] = Wq;  ca.dst[2] = WqB;  ca.n[2] = 1024 * 1024;
  ca.src[3] = Wk;  ca.dst[3] = WkB;  ca.n[3] = 1024 * 1024;
  ca.src[4] = Wv;  ca.dst[4] = WvB;  ca.n[4] = 1024 * 1024;
  ca.src[5] = Wo;  ca.dst[5] = WoB;  ca.n[5] = 1024 * 1024;
  cast_multi<<<dim3(4096, 6), dim3(256), 0, stream>>>(ca);
  mask_bias<<<dim3(32), dim3(256), 0, stream>>>(msk, mbf, B_ * LKV_);

  gemm_bt<0><<<dim3(16, 32), dim3(256), 0, stream>>>(decB, WqB, bq, (void*)Qb,  4096, 1024, 1024);
  gemm_bt<0><<<dim3(16, 64), dim3(256), 0, stream>>>(encB, WkB, bk, (void*)Kb,  8192, 1024, 1024);
  gemm_bt<1><<<dim3(16, 64), dim3(256), 0, stream>>>(encB, WvB, bv, (void*)Vtb, 8192, 1024, 1024);

  attn_fwd<<<dim3(8, 16, 4), dim3(256), 0, stream>>>(Qb, Kb, Vtb, mbf, AO);

  gemm_bt<2><<<dim3(16, 32), dim3(256), 0, stream>>>(AO, WoB, bo, d_out, 4096, 1024, 1024);
}